// Round 4
// baseline (480.304 us; speedup 1.0000x reference)
//
#include <hip/hip_runtime.h>
#include <hip/hip_bf16.h>

#define DIM 256
#define HIST 200
#define MPAD2 224         // 14 m-tiles of 16 (2 chunks x 7 tiles)
#define CHROWS 112        // rows per chunk
#define BATCH 2048
#define HSTRIDE 280       // bf16/row: 560 B == 12 dwords mod 32 banks -> <=2-way on b128
#define EPSF 1e-12f

typedef __bf16 bf16x8 __attribute__((ext_vector_type(8)));
typedef float f32x4 __attribute__((ext_vector_type(4)));

__device__ __forceinline__ unsigned short f2bf(float f) {
    union { float f; unsigned u; } v; v.f = f;
    unsigned r = (v.u + 0x7fffu + ((v.u >> 16) & 1u)) >> 16;
    return (unsigned short)r;
}
__device__ __forceinline__ unsigned pkbf(float a, float b) {   // v_cvt_pk_bf16_f32
    __hip_bfloat162 t = __float22bfloat162_rn(float2{a, b});
    union { __hip_bfloat162 h; unsigned u; } v; v.h = t; return v.u;
}
__device__ __forceinline__ float bf_lo(unsigned u) {
    union { unsigned u; float f; } v; v.u = u << 16; return v.f;
}
__device__ __forceinline__ float bf_hi(unsigned u) {
    union { unsigned u; float f; } v; v.u = u & 0xffff0000u; return v.f;
}

// ---------- fused prep (one launch) ----------
// bid [0,16):    W1t2[g*2048 + n*8 + j] = bf16(W1[(g*8+j)*DIM + n])
// bid [16,240):  Ct2[((m>>4)*4 + ((m>>2)&3))*1024 + n*4 + (m&3)] = (P@W2+bias)[m][n] (0 if m>=200)
// bid [240,496): sInv[row] = min(1, 1/max(||venue[row]||,eps)), grid-stride, wave per row
__global__ __launch_bounds__(256) void k_prep(
    const float* __restrict__ W1, const float* __restrict__ P,
    const float* __restrict__ W2, const float* __restrict__ bias,
    const float* __restrict__ venue,
    unsigned short* __restrict__ W1t2, float* __restrict__ Ct2,
    float* __restrict__ sInv, int nV) {
    const int bid = blockIdx.x, tid = threadIdx.x;
    if (bid < 16) {
#pragma unroll
        for (int it = 0; it < 16; ++it) {
            int idx = bid * 4096 + it * 256 + tid;      // [0, 65536)
            int g = idx >> 11, rem = idx & 2047;
            int n = rem >> 3, j = rem & 7;
            W1t2[idx] = f2bf(W1[(g * 8 + j) * DIM + n]);
        }
    } else if (bid < 240) {
        const int h = bid - 16;                          // m index [0,224)
        __shared__ float Prow[DIM];
        const int e = tid;
        float acc = 0.f;
        if (h < HIST) {
            Prow[e] = P[h * DIM + e];
            __syncthreads();
            acc = bias[h * DIM + e];
#pragma unroll 8
            for (int d = 0; d < DIM; ++d) acc += Prow[d] * W2[d * DIM + e];
        }
        Ct2[((h >> 4) * 4 + ((h >> 2) & 3)) * 1024 + e * 4 + (h & 3)] = acc;
    } else {
        const int lane = tid & 63;
        for (int row = (bid - 240) * 4 + (tid >> 6); row < nV; row += 1024) {
            const float4 g = *(const float4*)(venue + (size_t)row * DIM + lane * 4);
            float ss = g.x * g.x + g.y * g.y + g.z * g.z + g.w * g.w;
#pragma unroll
            for (int off = 32; off > 0; off >>= 1) ss += __shfl_xor(ss, off);
            if (lane == 0) sInv[row] = fminf(1.f, 1.f / fmaxf(sqrtf(ss), EPSF));
        }
    }
}

// ---------- main: 512 threads (8 waves), 2 blocks/CU, 2 m-chunks of 112 rows ----------
__global__ __launch_bounds__(512, 4) void k_main(
    const int* __restrict__ batch_u, const int* __restrict__ batch_v,
    const int* __restrict__ batch_history,
    const float* __restrict__ user_emb, const float* __restrict__ venue_emb,
    const float* __restrict__ Ct2, const unsigned short* __restrict__ W1t2,
    const float* __restrict__ sInv,
    const float* __restrict__ a_ptr, float* __restrict__ out) {

    __shared__ unsigned short histS[CHROWS * HSTRIDE];  // 62720 B
    __shared__ float scaleS[MPAD2];
    __shared__ int idxS[MPAD2];
    __shared__ float lArr[DIM];
    __shared__ float redS[4][4];
    __shared__ float invS[3];

    const int b = blockIdx.x;
    const int tid = threadIdx.x;
    const int wave = tid >> 6;        // 0..7
    const int lane = tid & 63;
    const int quad = lane >> 4;
    const int l16 = lane & 15;
    const int n0 = wave * 32 + l16 * 2;   // this lane owns columns n0, n0+1

    if (tid < MPAD2) {
        int m = (tid < HIST) ? tid : 0;
        int ix = batch_history[b * HIST + m];
        idxS[tid] = ix;
        scaleS[tid] = (tid < HIST) ? sInv[ix] : 0.f;
    }
    float ut = 0.f, vt = 0.f;
    if (tid < DIM) {
        ut = user_emb[(size_t)batch_u[b] * DIM + tid];
        vt = venue_emb[(size_t)batch_v[b] * DIM + tid];
    }
    __syncthreads();

    const float a_val = a_ptr[0];
    float Ssum[2] = {0.f, 0.f}, Lnum[2] = {0.f, 0.f};

    for (int chunk = 0; chunk < 2; ++chunk) {
        const int base = chunk * CHROWS;
        const int r0 = wave * 14;              // local rows [r0, r0+14)
        // ---- stage 14 rows/wave in 2 batches of 7 (28 VGPR in flight) ----
#pragma unroll
        for (int half = 0; half < 2; ++half) {
            float4 buf[7];
#pragma unroll
            for (int j = 0; j < 7; ++j)
                buf[j] = *(const float4*)(venue_emb +
                         (size_t)idxS[base + r0 + half * 7 + j] * DIM + lane * 4);
#pragma unroll
            for (int j = 0; j < 7; ++j) {
                int lr = r0 + half * 7 + j;
                float s = scaleS[base + lr];
                uint2 pk = { pkbf(buf[j].x * s, buf[j].y * s),
                             pkbf(buf[j].z * s, buf[j].w * s) };
                *(uint2*)&histS[lr * HSTRIDE + lane * 4] = pk;
            }
        }
        // acc init while staging stores drain
        f32x4 acc[7][2];
#pragma unroll
        for (int t = 0; t < 7; ++t)
#pragma unroll
            for (int i = 0; i < 2; ++i)
                acc[t][i] = *(const f32x4*)(Ct2 + ((chunk * 7 + t) * 4 + quad) * 1024 + (n0 + i) * 4);
        __syncthreads();

        // ---- MFMA: 7 m-tiles x 2 n-cols per lane ----
#pragma unroll
        for (int k = 0; k < 8; ++k) {
            bf16x8 Bf0 = *(const bf16x8*)(const void*)(W1t2 + (k * 4 + quad) * 2048 + n0 * 8);
            bf16x8 Bf1 = *(const bf16x8*)(const void*)(W1t2 + (k * 4 + quad) * 2048 + (n0 + 1) * 8);
#pragma unroll
            for (int t = 0; t < 7; ++t) {
                const bf16x8 Af =
                    *(const bf16x8*)(const void*)(&histS[(t * 16 + l16) * HSTRIDE + k * 32 + quad * 8]);
                acc[t][0] = __builtin_amdgcn_mfma_f32_16x16x32_bf16(Af, Bf0, acc[t][0], 0, 0, 0);
                acc[t][1] = __builtin_amdgcn_mfma_f32_16x16x32_bf16(Af, Bf1, acc[t][1], 0, 0, 0);
            }
        }

        // ---- tanh + exp + weighted sum (h in (-1,1): no max subtraction) ----
#pragma unroll
        for (int t = 0; t < 7; ++t)
#pragma unroll
            for (int r = 0; r < 4; ++r) {
                int lm = t * 16 + quad * 4 + r;
                if (base + lm < HIST) {
                    unsigned hv = *(const unsigned*)&histS[lm * HSTRIDE + n0];
                    float x0 = acc[t][0][r], x1 = acc[t][1][r];
                    float th0 = 1.f - 2.f * __builtin_amdgcn_rcpf(__expf(2.f * x0) + 1.f);
                    float th1 = 1.f - 2.f * __builtin_amdgcn_rcpf(__expf(2.f * x1) + 1.f);
                    float e0 = __expf(th0), e1 = __expf(th1);
                    Ssum[0] += e0; Lnum[0] += e0 * bf_lo(hv);
                    Ssum[1] += e1; Lnum[1] += e1 * bf_hi(hv);
                }
            }
        __syncthreads();   // protect histS before next chunk's stores
    }

#pragma unroll
    for (int i = 0; i < 2; ++i) {
        Ssum[i] += __shfl_xor(Ssum[i], 16); Ssum[i] += __shfl_xor(Ssum[i], 32);
        Lnum[i] += __shfl_xor(Lnum[i], 16); Lnum[i] += __shfl_xor(Lnum[i], 32);
    }
    if (quad == 0)
        *(float2*)&lArr[n0] = float2{ Lnum[0] * __builtin_amdgcn_rcpf(Ssum[0]) + a_val,
                                      Lnum[1] * __builtin_amdgcn_rcpf(Ssum[1]) + a_val };
    __syncthreads();

    // ---- epilogue on waves 0..3 (tid < 256): s = u^ + l^ - v^ ; out = ||s|| ----
    const float lt = (tid < DIM) ? lArr[tid] : 0.f;
    float pu = ut * ut, pv = vt * vt, pl = lt * lt;
#pragma unroll
    for (int off = 32; off > 0; off >>= 1) {
        pu += __shfl_xor(pu, off);
        pv += __shfl_xor(pv, off);
        pl += __shfl_xor(pl, off);
    }
    if (lane == 0 && wave < 4) { redS[wave][0] = pu; redS[wave][1] = pv; redS[wave][2] = pl; }
    __syncthreads();
    if (tid == 0) {
        float su = 0.f, sv = 0.f, sl = 0.f;
        for (int w = 0; w < 4; ++w) { su += redS[w][0]; sv += redS[w][1]; sl += redS[w][2]; }
        invS[0] = 1.f / fmaxf(sqrtf(su), EPSF);
        invS[1] = 1.f / fmaxf(sqrtf(sv), EPSF);
        invS[2] = 1.f / fmaxf(sqrtf(sl), EPSF);
    }
    __syncthreads();
    float s = ut * invS[0] + lt * invS[2] - vt * invS[1];
    float s2 = s * s;
#pragma unroll
    for (int off = 32; off > 0; off >>= 1) s2 += __shfl_xor(s2, off);
    if (lane == 0 && wave < 4) redS[wave][3] = s2;
    __syncthreads();
    if (tid == 0) out[b] = sqrtf(redS[0][3] + redS[1][3] + redS[2][3] + redS[3][3]);
}

extern "C" void kernel_launch(void* const* d_in, const int* in_sizes, int n_in,
                              void* d_out, int out_size, void* d_ws, size_t ws_size,
                              hipStream_t stream) {
    const int* batch_u = (const int*)d_in[0];
    const int* batch_v = (const int*)d_in[1];
    const int* batch_history = (const int*)d_in[2];
    // d_in[3], d_in[4]: olc inputs, unused by the reference forward
    const float* user_emb = (const float*)d_in[5];
    const float* venue_emb = (const float*)d_in[6];
    const float* W1 = (const float*)d_in[7];
    const float* W2 = (const float*)d_in[8];
    const float* P = (const float*)d_in[9];
    const float* bias = (const float*)d_in[10];
    const float* a = (const float*)d_in[11];
    float* out = (float*)d_out;

    const int nV = in_sizes[6] / DIM;

    // ws: Ct2 [14*4*1024] f32 (229376 B) | W1t2 [32*256*8] bf16 (131072 B) | sInv [nV] f32
    float* Ct2 = (float*)d_ws;
    unsigned short* W1t2 = (unsigned short*)((char*)d_ws + 229376);
    float* sInv = (float*)((char*)d_ws + 229376 + 131072);

    k_prep<<<496, 256, 0, stream>>>(W1, P, W2, bias, venue_emb, W1t2, Ct2, sInv, nV);
    k_main<<<BATCH, 512, 0, stream>>>(batch_u, batch_v, batch_history,
                                      user_emb, venue_emb, Ct2, W1t2, sInv, a, out);
}

// Round 5
// 420.539 us; speedup vs baseline: 1.1421x; 1.1421x over previous
//
#include <hip/hip_runtime.h>
#include <hip/hip_bf16.h>

#define DIM 256
#define HIST 200
#define MROWS 208         // 13 m-tiles of 16 (chunk0: 7 tiles, chunk1: 6 tiles)
#define BATCH 2048
#define EPSF 1e-12f

typedef __bf16 bf16x8 __attribute__((ext_vector_type(8)));
typedef float f32x4 __attribute__((ext_vector_type(4)));

__device__ __forceinline__ unsigned short f2bf(float f) {
    union { float f; unsigned u; } v; v.f = f;
    unsigned r = (v.u + 0x7fffu + ((v.u >> 16) & 1u)) >> 16;
    return (unsigned short)r;
}
__device__ __forceinline__ unsigned pkbf(float a, float b) {   // v_cvt_pk_bf16_f32
    __hip_bfloat162 t = __float22bfloat162_rn(float2{a, b});
    union { __hip_bfloat162 h; unsigned u; } v; v.h = t; return v.u;
}
__device__ __forceinline__ float bf_lo(unsigned u) {
    union { unsigned u; float f; } v; v.u = u << 16; return v.f;
}
__device__ __forceinline__ float bf_hi(unsigned u) {
    union { unsigned u; float f; } v; v.u = u & 0xffff0000u; return v.f;
}

// ---------- prep: W1t2 (bf16 B-operand layout) + Ct2 (P@W2+bias, MFMA-D layout) ----------
// bid [0,16):   W1t2[g*2048 + n*8 + j] = bf16(W1[(g*8+j)*DIM + n])   (g = k-group of 8)
// bid [16,240): Ct2[((m>>4)*4 + ((m>>2)&3))*1024 + n*4 + (m&3)] = (P@W2+bias)[m][n] (0 if m>=200)
__global__ __launch_bounds__(256) void k_prep(
    const float* __restrict__ W1, const float* __restrict__ P,
    const float* __restrict__ W2, const float* __restrict__ bias,
    unsigned short* __restrict__ W1t2, float* __restrict__ Ct2) {
    const int bid = blockIdx.x, tid = threadIdx.x;
    if (bid < 16) {
#pragma unroll
        for (int it = 0; it < 16; ++it) {
            int idx = bid * 4096 + it * 256 + tid;      // [0, 65536)
            int g = idx >> 11, rem = idx & 2047;
            int n = rem >> 3, j = rem & 7;
            W1t2[idx] = f2bf(W1[(g * 8 + j) * DIM + n]);
        }
    } else {
        const int h = bid - 16;                          // m index [0,224)
        __shared__ float Prow[DIM];
        const int e = tid;
        float acc = 0.f;
        if (h < HIST) {
            Prow[e] = P[h * DIM + e];
            __syncthreads();
            acc = bias[h * DIM + e];
#pragma unroll 8
            for (int d = 0; d < DIM; ++d) acc += Prow[d] * W2[d * DIM + e];
        }
        if (h < 224)
            Ct2[((h >> 4) * 4 + ((h >> 2) & 3)) * 1024 + e * 4 + (h & 3)] = acc;
    }
}

// ---- per-chunk worker: stage TILES*16 rows -> swizzled bf16 LDS, MFMA, tanh/exp ----
// histS layout: element e of local row r lives at r*256 + ((e>>3)^(r&7))*8 + (e&7)
template<int TILES>
__device__ __forceinline__ void process_chunk(
    int chunk_base, const int* idxS, const float* __restrict__ venue_emb,
    unsigned short* histS, const float* __restrict__ Ct2,
    const unsigned short* __restrict__ W1t2,
    int wave, int lane, int quad, int l16, int n0,
    float a_val, float* Ssum, float* Lnum) {

    const int HALF = TILES;              // rows per wave = 2*TILES, staged in 2 halves
    const int r0 = wave * 2 * TILES;
#pragma unroll
    for (int half = 0; half < 2; ++half) {
        float4 buf[HALF];
#pragma unroll
        for (int j = 0; j < HALF; ++j)
            buf[j] = *(const float4*)(venue_emb +
                     (size_t)idxS[chunk_base + r0 + half * HALF + j] * DIM + lane * 4);
#pragma unroll
        for (int j = 0; j < HALF; ++j) {
            int lr = r0 + half * HALF + j;
            int m = chunk_base + lr;
            float4 g = buf[j];
            float ss = g.x * g.x + g.y * g.y + g.z * g.z + g.w * g.w;
            ss += __shfl_xor(ss, 1);  ss += __shfl_xor(ss, 2);  ss += __shfl_xor(ss, 4);
            ss += __shfl_xor(ss, 8);  ss += __shfl_xor(ss, 16); ss += __shfl_xor(ss, 32);
            float s = (ss > 1.f) ? __builtin_amdgcn_rsqf(ss) : 1.f;   // min(1, 1/||g||)
            if (m >= HIST) s = 0.f;                                    // zero-pad rows
            uint2 pk = { pkbf(g.x * s, g.y * s), pkbf(g.z * s, g.w * s) };
            int gr = (lane >> 1) ^ (lr & 7);
            *(uint2*)&histS[lr * 256 + gr * 8 + (lane & 1) * 4] = pk;
        }
    }
    __syncthreads();

    // acc init from Ct2 (coalesced), then MFMA
    f32x4 acc[TILES][2];
#pragma unroll
    for (int t = 0; t < TILES; ++t)
#pragma unroll
        for (int i = 0; i < 2; ++i)
            acc[t][i] = *(const f32x4*)(Ct2 + (((chunk_base >> 4) + t) * 4 + quad) * 1024 + (n0 + i) * 4);

#pragma unroll
    for (int k = 0; k < 8; ++k) {
        bf16x8 Bf0 = *(const bf16x8*)(const void*)(W1t2 + (k * 4 + quad) * 2048 + n0 * 8);
        bf16x8 Bf1 = *(const bf16x8*)(const void*)(W1t2 + (k * 4 + quad) * 2048 + (n0 + 1) * 8);
#pragma unroll
        for (int t = 0; t < TILES; ++t) {
            int gr = (k * 4 + quad) ^ (l16 & 7);
            const bf16x8 Af = *(const bf16x8*)(const void*)(&histS[(t * 16 + l16) * 256 + gr * 8]);
            acc[t][0] = __builtin_amdgcn_mfma_f32_16x16x32_bf16(Af, Bf0, acc[t][0], 0, 0, 0);
            acc[t][1] = __builtin_amdgcn_mfma_f32_16x16x32_bf16(Af, Bf1, acc[t][1], 0, 0, 0);
        }
    }

    // tanh + exp + weighted sum (h in (-1,1): no max subtraction needed)
#pragma unroll
    for (int t = 0; t < TILES; ++t)
#pragma unroll
        for (int r = 0; r < 4; ++r) {
            int lm = t * 16 + quad * 4 + r;
            int m = chunk_base + lm;
            if (m < HIST) {   // compile-time true except last tile (runtime quad guard)
                int gr = (wave * 4 + (l16 >> 2)) ^ (lm & 7);
                unsigned hv = *(const unsigned*)&histS[lm * 256 + gr * 8 + (l16 & 3) * 2];
                float x0 = acc[t][0][r], x1 = acc[t][1][r];
                float th0 = 1.f - 2.f * __builtin_amdgcn_rcpf(__expf(2.f * x0) + 1.f);
                float th1 = 1.f - 2.f * __builtin_amdgcn_rcpf(__expf(2.f * x1) + 1.f);
                float e0 = __expf(th0), e1 = __expf(th1);
                Ssum[0] += e0; Lnum[0] += e0 * bf_lo(hv);
                Ssum[1] += e1; Lnum[1] += e1 * bf_hi(hv);
            }
        }
    __syncthreads();   // protect histS before the next chunk's stores
}

// ---------- main: 512 threads (8 waves), 2 blocks/CU, chunks of 112 + 96 rows ----------
__global__ __launch_bounds__(512, 2) void k_main(
    const int* __restrict__ batch_u, const int* __restrict__ batch_v,
    const int* __restrict__ batch_history,
    const float* __restrict__ user_emb, const float* __restrict__ venue_emb,
    const float* __restrict__ Ct2, const unsigned short* __restrict__ W1t2,
    const float* __restrict__ a_ptr, float* __restrict__ out) {

    __shared__ __align__(16) unsigned short histS[112 * 256];  // 57344 B, swizzled
    __shared__ int idxS[MROWS];
    __shared__ float lArr[DIM];
    __shared__ float redS[4][4];
    __shared__ float invS[3];

    const int b = blockIdx.x;
    const int tid = threadIdx.x;
    const int wave = tid >> 6;        // 0..7
    const int lane = tid & 63;
    const int quad = lane >> 4;
    const int l16 = lane & 15;
    const int n0 = wave * 32 + l16 * 2;   // this lane owns columns n0, n0+1

    if (tid < MROWS)
        idxS[tid] = batch_history[b * HIST + ((tid < HIST) ? tid : 0)];
    float ut = 0.f, vt = 0.f;
    if (tid < DIM) {
        ut = user_emb[(size_t)batch_u[b] * DIM + tid];
        vt = venue_emb[(size_t)batch_v[b] * DIM + tid];
    }
    __syncthreads();

    const float a_val = a_ptr[0];
    float Ssum[2] = {0.f, 0.f}, Lnum[2] = {0.f, 0.f};

    process_chunk<7>(0,   idxS, venue_emb, histS, Ct2, W1t2,
                     wave, lane, quad, l16, n0, a_val, Ssum, Lnum);
    process_chunk<6>(112, idxS, venue_emb, histS, Ct2, W1t2,
                     wave, lane, quad, l16, n0, a_val, Ssum, Lnum);

#pragma unroll
    for (int i = 0; i < 2; ++i) {
        Ssum[i] += __shfl_xor(Ssum[i], 16); Ssum[i] += __shfl_xor(Ssum[i], 32);
        Lnum[i] += __shfl_xor(Lnum[i], 16); Lnum[i] += __shfl_xor(Lnum[i], 32);
    }
    if (quad == 0)
        *(float2*)&lArr[n0] = float2{ Lnum[0] * __builtin_amdgcn_rcpf(Ssum[0]) + a_val,
                                      Lnum[1] * __builtin_amdgcn_rcpf(Ssum[1]) + a_val };
    __syncthreads();

    // ---- epilogue: s = u^ + l^ - v^ ; out = ||s|| (waves 4..7 contribute zeros) ----
    const float lt = (tid < DIM) ? lArr[tid] : 0.f;
    float pu = ut * ut, pv = vt * vt, pl = lt * lt;
#pragma unroll
    for (int off = 32; off > 0; off >>= 1) {
        pu += __shfl_xor(pu, off);
        pv += __shfl_xor(pv, off);
        pl += __shfl_xor(pl, off);
    }
    if (lane == 0 && wave < 4) { redS[wave][0] = pu; redS[wave][1] = pv; redS[wave][2] = pl; }
    __syncthreads();
    if (tid == 0) {
        float su = 0.f, sv = 0.f, sl = 0.f;
        for (int w = 0; w < 4; ++w) { su += redS[w][0]; sv += redS[w][1]; sl += redS[w][2]; }
        invS[0] = 1.f / fmaxf(sqrtf(su), EPSF);
        invS[1] = 1.f / fmaxf(sqrtf(sv), EPSF);
        invS[2] = 1.f / fmaxf(sqrtf(sl), EPSF);
    }
    __syncthreads();
    float s = ut * invS[0] + lt * invS[2] - vt * invS[1];
    float s2 = s * s;
#pragma unroll
    for (int off = 32; off > 0; off >>= 1) s2 += __shfl_xor(s2, off);
    if (lane == 0 && wave < 4) redS[wave][3] = s2;
    __syncthreads();
    if (tid == 0) out[b] = sqrtf(redS[0][3] + redS[1][3] + redS[2][3] + redS[3][3]);
}

extern "C" void kernel_launch(void* const* d_in, const int* in_sizes, int n_in,
                              void* d_out, int out_size, void* d_ws, size_t ws_size,
                              hipStream_t stream) {
    const int* batch_u = (const int*)d_in[0];
    const int* batch_v = (const int*)d_in[1];
    const int* batch_history = (const int*)d_in[2];
    // d_in[3], d_in[4]: olc inputs, unused by the reference forward
    const float* user_emb = (const float*)d_in[5];
    const float* venue_emb = (const float*)d_in[6];
    const float* W1 = (const float*)d_in[7];
    const float* W2 = (const float*)d_in[8];
    const float* P = (const float*)d_in[9];
    const float* bias = (const float*)d_in[10];
    const float* a = (const float*)d_in[11];
    float* out = (float*)d_out;

    // ws: Ct2 [14*4*1024] f32 (229376 B) | W1t2 [32*256*8] bf16 (131072 B)
    float* Ct2 = (float*)d_ws;
    unsigned short* W1t2 = (unsigned short*)((char*)d_ws + 229376);

    k_prep<<<240, 256, 0, stream>>>(W1, P, W2, bias, W1t2, Ct2);
    k_main<<<BATCH, 512, 0, stream>>>(batch_u, batch_v, batch_history,
                                      user_emb, venue_emb, Ct2, W1t2, a, out);
}

// Round 6
// 398.703 us; speedup vs baseline: 1.2047x; 1.0548x over previous
//
#include <hip/hip_runtime.h>
#include <hip/hip_bf16.h>

#define DIM 256
#define HIST 200
#define MROWS 208         // 13 m-tiles of 16 (chunk0: 7 tiles, chunk1: 6 tiles)
#define BATCH 2048
#define EPSF 1e-12f

typedef __bf16 bf16x8 __attribute__((ext_vector_type(8)));
typedef float f32x4 __attribute__((ext_vector_type(4)));

__device__ __forceinline__ unsigned short f2bf(float f) {
    union { float f; unsigned u; } v; v.f = f;
    unsigned r = (v.u + 0x7fffu + ((v.u >> 16) & 1u)) >> 16;
    return (unsigned short)r;
}
__device__ __forceinline__ unsigned pkbf(float a, float b) {   // v_cvt_pk_bf16_f32
    __hip_bfloat162 t = __float22bfloat162_rn(float2{a, b});
    union { __hip_bfloat162 h; unsigned u; } v; v.h = t; return v.u;
}
__device__ __forceinline__ float bf_lo(unsigned u) {
    union { unsigned u; float f; } v; v.u = u << 16; return v.f;
}
__device__ __forceinline__ float bf_hi(unsigned u) {
    union { unsigned u; float f; } v; v.u = u & 0xffff0000u; return v.f;
}

// ---------- prep: W1t2 + Ct2 + sInv in one launch ----------
// bid [0,16):    W1t2[g*2048 + n*8 + j] = bf16(W1[(g*8+j)*DIM + n])   (g = k-group of 8)
// bid [16,240):  Ct2[((m>>4)*4 + ((m>>2)&3))*1024 + n*4 + (m&3)] = (P@W2+bias)[m][n] (0 if m>=200)
// bid [240,752): sInv[row] = min(1, 1/max(||venue[row]||,eps)), grid-stride, wave per row
__global__ __launch_bounds__(256) void k_prep(
    const float* __restrict__ W1, const float* __restrict__ P,
    const float* __restrict__ W2, const float* __restrict__ bias,
    const float* __restrict__ venue,
    unsigned short* __restrict__ W1t2, float* __restrict__ Ct2,
    float* __restrict__ sInv, int nV) {
    const int bid = blockIdx.x, tid = threadIdx.x;
    if (bid < 16) {
#pragma unroll
        for (int it = 0; it < 16; ++it) {
            int idx = bid * 4096 + it * 256 + tid;      // [0, 65536)
            int g = idx >> 11, rem = idx & 2047;
            int n = rem >> 3, j = rem & 7;
            W1t2[idx] = f2bf(W1[(g * 8 + j) * DIM + n]);
        }
    } else if (bid < 240) {
        const int h = bid - 16;                          // m index [0,224)
        __shared__ float Prow[DIM];
        const int e = tid;
        float acc = 0.f;
        if (h < HIST) {
            Prow[e] = P[h * DIM + e];
            __syncthreads();
            acc = bias[h * DIM + e];
#pragma unroll 8
            for (int d = 0; d < DIM; ++d) acc += Prow[d] * W2[d * DIM + e];
        }
        Ct2[((h >> 4) * 4 + ((h >> 2) & 3)) * 1024 + e * 4 + (h & 3)] = acc;
    } else {
        const int lane = tid & 63;
        const int nblk = gridDim.x - 240;                // 512
        for (int row = (bid - 240) * 4 + (tid >> 6); row < nV; row += nblk * 4) {
            const float4 g = *(const float4*)(venue + (size_t)row * DIM + lane * 4);
            float ss = g.x * g.x + g.y * g.y + g.z * g.z + g.w * g.w;
#pragma unroll
            for (int off = 32; off > 0; off >>= 1) ss += __shfl_xor(ss, off);
            if (lane == 0) sInv[row] = (ss > 1.f) ? __builtin_amdgcn_rsqf(ss) : 1.f;
        }
    }
}

// ---- per-chunk worker: stage TILES*16 rows -> swizzled bf16 LDS, MFMA, tanh/exp ----
// histS layout: element e of local row r lives at r*256 + ((e>>3)^(r&7))*8 + (e&7)
template<int TILES>
__device__ __forceinline__ void process_chunk(
    int chunk_base, const int* idxS, const float* scaleS,
    const float* __restrict__ venue_emb,
    unsigned short* histS, const float* __restrict__ Ct2,
    const unsigned short* __restrict__ W1t2,
    int wave, int lane, int quad, int l16, int n0,
    float* Ssum, float* Lnum) {

    const int ROWS = TILES * 2;          // rows per wave
    const int r0 = wave * ROWS;

    // ---- stage: 4-deep software pipeline, no cross-lane reduce (sInv precomputed) ----
    float4 buf[4];
#pragma unroll
    for (int j = 0; j < 4; ++j)
        buf[j] = *(const float4*)(venue_emb +
                 (size_t)idxS[chunk_base + r0 + j] * DIM + lane * 4);
#pragma unroll
    for (int j = 0; j < ROWS; ++j) {
        float4 g = buf[j & 3];
        if (j + 4 < ROWS)
            buf[j & 3] = *(const float4*)(venue_emb +
                         (size_t)idxS[chunk_base + r0 + j + 4] * DIM + lane * 4);
        int lr = r0 + j;
        float s = scaleS[chunk_base + lr];               // 0 for pad rows (m>=200)
        uint2 pk = { pkbf(g.x * s, g.y * s), pkbf(g.z * s, g.w * s) };
        int gr = (lane >> 1) ^ (lr & 7);
        *(uint2*)&histS[lr * 256 + gr * 8 + (lane & 1) * 4] = pk;
    }
    __syncthreads();

    // ---- acc init from Ct2, then MFMA (acc lives in AGPRs) ----
    f32x4 acc[TILES][2];
#pragma unroll
    for (int t = 0; t < TILES; ++t)
#pragma unroll
        for (int i = 0; i < 2; ++i)
            acc[t][i] = *(const f32x4*)(Ct2 + (((chunk_base >> 4) + t) * 4 + quad) * 1024 + (n0 + i) * 4);

#pragma unroll 2   // limit B-fragment hoisting (VGPR cap is 64)
    for (int k = 0; k < 8; ++k) {
        bf16x8 Bf0 = *(const bf16x8*)(const void*)(W1t2 + (k * 4 + quad) * 2048 + n0 * 8);
        bf16x8 Bf1 = *(const bf16x8*)(const void*)(W1t2 + (k * 4 + quad) * 2048 + (n0 + 1) * 8);
        int gr = (k * 4 + quad) ^ (l16 & 7);
#pragma unroll
        for (int t = 0; t < TILES; ++t) {
            const bf16x8 Af = *(const bf16x8*)(const void*)(&histS[(t * 16 + l16) * 256 + gr * 8]);
            acc[t][0] = __builtin_amdgcn_mfma_f32_16x16x32_bf16(Af, Bf0, acc[t][0], 0, 0, 0);
            acc[t][1] = __builtin_amdgcn_mfma_f32_16x16x32_bf16(Af, Bf1, acc[t][1], 0, 0, 0);
        }
    }

    // ---- tanh + exp + weighted sum (h in (-1,1): no max subtraction needed) ----
#pragma unroll
    for (int t = 0; t < TILES; ++t)
#pragma unroll
        for (int r = 0; r < 4; ++r) {
            int lm = t * 16 + quad * 4 + r;
            int m = chunk_base + lm;
            if (m < HIST) {   // compile-time true except the last tile
                int gr = (wave * 4 + (l16 >> 2)) ^ (lm & 7);
                unsigned hv = *(const unsigned*)&histS[lm * 256 + gr * 8 + (l16 & 3) * 2];
                float x0 = acc[t][0][r], x1 = acc[t][1][r];
                float th0 = 1.f - 2.f * __builtin_amdgcn_rcpf(__expf(2.f * x0) + 1.f);
                float th1 = 1.f - 2.f * __builtin_amdgcn_rcpf(__expf(2.f * x1) + 1.f);
                float e0 = __expf(th0), e1 = __expf(th1);
                Ssum[0] += e0; Lnum[0] += e0 * bf_lo(hv);
                Ssum[1] += e1; Lnum[1] += e1 * bf_hi(hv);
            }
        }
    __syncthreads();   // protect histS before the next chunk's stores
}

// ---------- main: 512 threads (8 waves), target 2 blocks/CU (4 waves/SIMD) ----------
__global__ __launch_bounds__(512, 4) void k_main(
    const int* __restrict__ batch_u, const int* __restrict__ batch_v,
    const int* __restrict__ batch_history,
    const float* __restrict__ user_emb, const float* __restrict__ venue_emb,
    const float* __restrict__ Ct2, const unsigned short* __restrict__ W1t2,
    const float* __restrict__ sInv,
    const float* __restrict__ a_ptr, float* __restrict__ out) {

    __shared__ __align__(16) unsigned short histS[112 * 256];  // 57344 B, swizzled
    __shared__ int idxS[MROWS];
    __shared__ float scaleS[MROWS];
    __shared__ float lArr[DIM];
    __shared__ float redS[4][4];
    __shared__ float invS[3];

    const int b = blockIdx.x;
    const int tid = threadIdx.x;
    const int wave = tid >> 6;        // 0..7
    const int lane = tid & 63;
    const int quad = lane >> 4;
    const int l16 = lane & 15;
    const int n0 = wave * 32 + l16 * 2;   // this lane owns columns n0, n0+1

    if (tid < MROWS) {
        int ix = batch_history[b * HIST + ((tid < HIST) ? tid : 0)];
        idxS[tid] = ix;
        scaleS[tid] = (tid < HIST) ? sInv[ix] : 0.f;
    }
    float ut = 0.f, vt = 0.f;
    if (tid < DIM) {
        ut = user_emb[(size_t)batch_u[b] * DIM + tid];
        vt = venue_emb[(size_t)batch_v[b] * DIM + tid];
    }
    __syncthreads();

    float Ssum[2] = {0.f, 0.f}, Lnum[2] = {0.f, 0.f};

    process_chunk<7>(0,   idxS, scaleS, venue_emb, histS, Ct2, W1t2,
                     wave, lane, quad, l16, n0, Ssum, Lnum);
    process_chunk<6>(112, idxS, scaleS, venue_emb, histS, Ct2, W1t2,
                     wave, lane, quad, l16, n0, Ssum, Lnum);

    const float a_val = a_ptr[0];
#pragma unroll
    for (int i = 0; i < 2; ++i) {
        Ssum[i] += __shfl_xor(Ssum[i], 16); Ssum[i] += __shfl_xor(Ssum[i], 32);
        Lnum[i] += __shfl_xor(Lnum[i], 16); Lnum[i] += __shfl_xor(Lnum[i], 32);
    }
    if (quad == 0)
        *(float2*)&lArr[n0] = float2{ Lnum[0] * __builtin_amdgcn_rcpf(Ssum[0]) + a_val,
                                      Lnum[1] * __builtin_amdgcn_rcpf(Ssum[1]) + a_val };
    __syncthreads();

    // ---- epilogue: s = u^ + l^ - v^ ; out = ||s|| (waves 4..7 contribute zeros) ----
    const float lt = (tid < DIM) ? lArr[tid] : 0.f;
    float pu = ut * ut, pv = vt * vt, pl = lt * lt;
#pragma unroll
    for (int off = 32; off > 0; off >>= 1) {
        pu += __shfl_xor(pu, off);
        pv += __shfl_xor(pv, off);
        pl += __shfl_xor(pl, off);
    }
    if (lane == 0 && wave < 4) { redS[wave][0] = pu; redS[wave][1] = pv; redS[wave][2] = pl; }
    __syncthreads();
    if (tid == 0) {
        float su = 0.f, sv = 0.f, sl = 0.f;
        for (int w = 0; w < 4; ++w) { su += redS[w][0]; sv += redS[w][1]; sl += redS[w][2]; }
        invS[0] = 1.f / fmaxf(sqrtf(su), EPSF);
        invS[1] = 1.f / fmaxf(sqrtf(sv), EPSF);
        invS[2] = 1.f / fmaxf(sqrtf(sl), EPSF);
    }
    __syncthreads();
    float s = ut * invS[0] + lt * invS[2] - vt * invS[1];
    float s2 = s * s;
#pragma unroll
    for (int off = 32; off > 0; off >>= 1) s2 += __shfl_xor(s2, off);
    if (lane == 0 && wave < 4) redS[wave][3] = s2;
    __syncthreads();
    if (tid == 0) out[b] = sqrtf(redS[0][3] + redS[1][3] + redS[2][3] + redS[3][3]);
}

extern "C" void kernel_launch(void* const* d_in, const int* in_sizes, int n_in,
                              void* d_out, int out_size, void* d_ws, size_t ws_size,
                              hipStream_t stream) {
    const int* batch_u = (const int*)d_in[0];
    const int* batch_v = (const int*)d_in[1];
    const int* batch_history = (const int*)d_in[2];
    // d_in[3], d_in[4]: olc inputs, unused by the reference forward
    const float* user_emb = (const float*)d_in[5];
    const float* venue_emb = (const float*)d_in[6];
    const float* W1 = (const float*)d_in[7];
    const float* W2 = (const float*)d_in[8];
    const float* P = (const float*)d_in[9];
    const float* bias = (const float*)d_in[10];
    const float* a = (const float*)d_in[11];
    float* out = (float*)d_out;

    const int nV = in_sizes[6] / DIM;

    // ws: Ct2 [14*4*1024] f32 (229376 B) | W1t2 [32*256*8] bf16 (131072 B) | sInv [nV] f32
    float* Ct2 = (float*)d_ws;
    unsigned short* W1t2 = (unsigned short*)((char*)d_ws + 229376);
    float* sInv = (float*)((char*)d_ws + 229376 + 131072);

    k_prep<<<752, 256, 0, stream>>>(W1, P, W2, bias, venue_emb, W1t2, Ct2, sInv, nV);
    k_main<<<BATCH, 512, 0, stream>>>(batch_u, batch_v, batch_history,
                                      user_emb, venue_emb, Ct2, W1t2, sInv, a, out);
}